// Round 6
// baseline (1425.782 us; speedup 1.0000x reference)
//
#include <hip/hip_runtime.h>
#include <hip/hip_bf16.h>

// ---------------------------------------------------------------------------
// Phase 1a: CSR build by dst, then gather-aggregate (unchanged)
// ---------------------------------------------------------------------------

__global__ __launch_bounds__(256) void sge_count(
    const int* __restrict__ dst, int* __restrict__ cnt, int nE) {
  int e = blockIdx.x * 256 + threadIdx.x;
  if (e >= nE) return;
  atomicAdd(&cnt[dst[e]], 1);
}

__global__ __launch_bounds__(256) void sge_blocksum(
    const int* __restrict__ cnt, int* __restrict__ bsum, int N) {
  int i = blockIdx.x * 256 + threadIdx.x;
  int v = (i < N) ? cnt[i] : 0;
#pragma unroll
  for (int o = 1; o < 64; o <<= 1) v += __shfl_xor(v, o);
  __shared__ int ws[4];
  int lane = threadIdx.x & 63, wid = threadIdx.x >> 6;
  if (lane == 0) ws[wid] = v;
  __syncthreads();
  if (threadIdx.x == 0)
    bsum[blockIdx.x] = ws[0] + ws[1] + ws[2] + ws[3];
}

__global__ __launch_bounds__(64) void sge_scan_top(
    int* __restrict__ bsum, int* __restrict__ offs, int nb, int N, int nE) {
  int lane = threadIdx.x;
  int carry = 0;
  for (int base = 0; base < nb; base += 64) {
    int i = base + lane;
    int v = (i < nb) ? bsum[i] : 0;
    int s = v;
#pragma unroll
    for (int o = 1; o < 64; o <<= 1) {
      int t = __shfl_up(s, o);
      if (lane >= o) s += t;
    }
    if (i < nb) bsum[i] = carry + s - v;  // exclusive
    carry += __shfl(s, 63);
  }
  if (lane == 0) offs[N] = nE;
}

__global__ __launch_bounds__(256) void sge_scan_block(
    const int* __restrict__ cnt, const int* __restrict__ bsum,
    int* __restrict__ offs, int* __restrict__ pos, int N) {
  int i = blockIdx.x * 256 + threadIdx.x;
  int v = (i < N) ? cnt[i] : 0;
  int lane = threadIdx.x & 63, wid = threadIdx.x >> 6;
  int s = v;
#pragma unroll
  for (int o = 1; o < 64; o <<= 1) {
    int t = __shfl_up(s, o);
    if (lane >= o) s += t;
  }
  __shared__ int ws[4];
  if (lane == 63) ws[wid] = s;
  __syncthreads();
  int wbase = 0;
  for (int w = 0; w < wid; ++w) wbase += ws[w];
  if (i < N) {
    int o = bsum[blockIdx.x] + wbase + s - v;
    offs[i] = o;
    pos[i] = o;
  }
}

__global__ __launch_bounds__(256) void sge_fill(
    const int* __restrict__ src, const int* __restrict__ dst,
    int* __restrict__ pos, int* __restrict__ sorted_src, int nE) {
  int e = blockIdx.x * 256 + threadIdx.x;
  if (e >= nE) return;
  int p = atomicAdd(&pos[dst[e]], 1);
  sorted_src[p] = src[e];
}

__global__ __launch_bounds__(256) void sge_gather(
    const float* __restrict__ x, const int* __restrict__ sorted_src,
    const int* __restrict__ offs, float* __restrict__ agg, int N) {
  int node = blockIdx.x * 2 + (threadIdx.x >> 7);
  int c = threadIdx.x & 127;
  if (node >= N) return;
  int e0 = offs[node], e1 = offs[node + 1];
  float acc = 0.0f;
  for (int e = e0; e < e1; ++e) {
    int s = sorted_src[e];
    acc += x[(size_t)s * 128 + c];
  }
  float dg = (float)(e1 - e0);
  agg[(size_t)node * 128 + c] = acc / fmaxf(dg, 1.0f);
}

// ---------------------------------------------------------------------------
// Phase 1b: z = agg @ W   (unchanged)
// ---------------------------------------------------------------------------
__global__ __launch_bounds__(256) void sge_gemm(
    const float* __restrict__ agg, const float* __restrict__ W,
    float* __restrict__ z) {
  __shared__ float xs[32][128];
  int n0 = blockIdx.x * 32;
  int t = threadIdx.x;
#pragma unroll
  for (int i = 0; i < 16; ++i) {
    int idx = t + i * 256;
    int r = idx >> 7;
    int c = idx & 127;
    xs[r][c] = agg[(long long)(n0 + r) * 128 + c];
  }
  __syncthreads();
  float acc[32];
#pragma unroll
  for (int r = 0; r < 32; ++r) acc[r] = 0.0f;
  for (int k = 0; k < 128; k += 4) {
    float w0 = W[(k + 0) * 256 + t];
    float w1 = W[(k + 1) * 256 + t];
    float w2 = W[(k + 2) * 256 + t];
    float w3 = W[(k + 3) * 256 + t];
#pragma unroll
    for (int r = 0; r < 32; ++r) {
      float4 xv = *(const float4*)&xs[r][k];
      acc[r] = fmaf(xv.x, w0, acc[r]);
      acc[r] = fmaf(xv.y, w1, acc[r]);
      acc[r] = fmaf(xv.z, w2, acc[r]);
      acc[r] = fmaf(xv.w, w3, acc[r]);
    }
  }
#pragma unroll
  for (int r = 0; r < 32; ++r) z[(long long)(n0 + r) * 256 + t] = acc[r];
}

// ---------------------------------------------------------------------------
// Phase 2 (v6): factorized softmin, no C array, no block barriers in loop.
//   wave 0: half0 = C_xy rows -> fab (needs gba = half1's P)
//           half1 = C_yx rows -> gba (needs fab = half0's P)
//   wave 1: half0 = C_xx rows -> faa (needs own), half1 = C_yy -> gbb (own)
// All cross-half exchange is intra-wave (lockstep): E via LDS + wave_barrier,
// group max via __shfl_xor(.,32). V <- V*V per halving step; final eps via
// V = exp2(1.5625 * log2(V)).  Per-lane regs: V[32] + ~12 scalars.
// ---------------------------------------------------------------------------
__device__ __forceinline__ float dot8(const float xr[8], float4 a0, float4 a1) {
  float d = xr[0] * a0.x;
  d = fmaf(xr[1], a0.y, d);
  d = fmaf(xr[2], a0.z, d);
  d = fmaf(xr[3], a0.w, d);
  d = fmaf(xr[4], a1.x, d);
  d = fmaf(xr[5], a1.y, d);
  d = fmaf(xr[6], a1.z, d);
  d = fmaf(xr[7], a1.w, d);
  return d;
}

__global__ __launch_bounds__(128, 6) void sge_energy(
    const float* __restrict__ z, const int* __restrict__ ep,
    const int* __restrict__ en, float* __restrict__ out, int nP) {
  __shared__ __align__(16) float zbuf[512];    // zx[256] | zy[256]
  __shared__ __align__(16) float nrm[64];      // nx[32] | ny[32]
  __shared__ __align__(16) float Ebuf[2][64];  // per-wave E vectors
  __shared__ float red[2];

  int t = threadIdx.x;
  int w = t >> 6;        // 0: {xy, yx}   1: {xx, yy}
  int l = t & 63;
  int row = l & 31;
  int own = l & 32;      // 0 = half0 (x-rows), 32 = half1 (y-rows)

  int pair = blockIdx.x;
  bool isPos = pair < nP;
  int idx = isPos ? pair : pair - nP;
  const int* E = isPos ? ep : en;
  int na = E[idx], nb = E[idx + nP];

  // load both z rows (512 floats), coalesced float4
  {
    const float4* za = (const float4*)(z + (size_t)na * 256);
    const float4* zb = (const float4*)(z + (size_t)nb * 256);
    ((float4*)zbuf)[t] = (t < 64) ? za[t] : zb[t - 64];
  }
  __syncthreads();

  if (t < 64) {
    const float* zr = zbuf + t * 8;
    float s = 0.0f;
#pragma unroll
    for (int d = 0; d < 8; ++d) s += zr[d] * zr[d];
    nrm[t] = s;
  }
  __syncthreads();

  const float* zx = zbuf;
  const float* zy = zbuf + 256;

  // operand selection:
  //  row: half0 -> x rows, half1 -> y rows (both waves)
  //  col: wave0 -> opposite set, wave1 -> same set
  const float* zrow = (own ? zy : zx) + row * 8;
  bool colIsX = (w == 0) ? (own != 0) : (own == 0);
  const float* pcol = colIsX ? zx : zy;
  const float* pn = colIsX ? nrm : (nrm + 32);
  float nself = nrm[own + row];

  float xr[8];
  {
    float4 a0 = ((const float4*)zrow)[0];
    float4 a1 = ((const float4*)zrow)[1];
    xr[0] = a0.x; xr[1] = a0.y; xr[2] = a0.z; xr[3] = a0.w;
    xr[4] = a1.x; xr[5] = a1.y; xr[6] = a1.z; xr[7] = a1.w;
  }

  const float RLNE = 1.44269504088896340736f;  // 1/ln2
  const float LN2 = 0.69314718055994530942f;
  const float LN32 = 3.46573590279972654709f;
  const float K20 = RLNE / 10.0f;              // k2 at eps=10

  // build V = 2^(-C * k2_0); C consumed transiently (not stored)
  float V[32];
#pragma unroll
  for (int j = 0; j < 32; ++j) {
    float4 a0 = ((const float4*)(pcol + j * 8))[0];
    float4 a1 = ((const float4*)(pcol + j * 8))[1];
    float d = dot8(xr, a0, a1);
    float sq = fmaf(-2.0f, d, nself + pn[j]);
    float C = __builtin_amdgcn_sqrtf(fmaxf(sq, 0.0f) + 1e-8f);
    V[j] = __builtin_amdgcn_exp2f(-C * K20);
  }

  // E slot: write own l; read partner half (wave0) or own half (wave1)
  float* Ew = Ebuf[w];
  int rb = (w == 0) ? (own ^ 32) : own;

  float P = 0.0f;
  float epsv = 10.0f;

#pragma unroll 1
  for (int it = 0; it < 9; ++it) {
    float eps = (it == 8) ? 0.05f : epsv;
    float k2 = RLNE / eps;
    float eln2 = eps * LN2;
    float c32 = eps * LN32;

    if (it == 8) {
      // eps 0.078125 -> 0.05: exponent scales by 1.5625
#pragma unroll
      for (int j = 0; j < 32; ++j)
        V[j] = __builtin_amdgcn_exp2f(1.5625f * __builtin_amdgcn_logf(V[j]));
    } else if (it > 0) {
#pragma unroll
      for (int j = 0; j < 32; ++j) V[j] *= V[j];
    }

    // group max of h over the OWNER half (this lane's P is one h value)
    float m = P;
    m = fmaxf(m, __shfl_xor(m, 1));
    m = fmaxf(m, __shfl_xor(m, 2));
    m = fmaxf(m, __shfl_xor(m, 4));
    m = fmaxf(m, __shfl_xor(m, 8));
    m = fmaxf(m, __shfl_xor(m, 16));

    Ew[l] = __builtin_amdgcn_exp2f((P - m) * k2);
    float mRead = (w == 0) ? __shfl_xor(m, 32) : m;
    __builtin_amdgcn_wave_barrier();

    float s0 = 0.f, s1 = 0.f, s2 = 0.f, s3 = 0.f;
#pragma unroll
    for (int jq = 0; jq < 8; ++jq) {
      float4 Ev = ((const float4*)(Ew + rb))[jq];
      s0 = fmaf(Ev.x, V[4 * jq + 0], s0);
      s1 = fmaf(Ev.y, V[4 * jq + 1], s1);
      s2 = fmaf(Ev.z, V[4 * jq + 2], s2);
      s3 = fmaf(Ev.w, V[4 * jq + 3], s3);
    }
    float s = fmaxf((s0 + s1) + (s2 + s3), 1e-37f);
    __builtin_amdgcn_wave_barrier();  // keep reads before next iter's write

    float res = c32 - mRead - eln2 * __builtin_amdgcn_logf(s);  // log2
    P = 0.5f * (P + res);
    epsv *= 0.5f;
  }

  // energy = (sum_{wave0} P - sum_{wave1} P) / 32
  float d = P;
#pragma unroll
  for (int o = 1; o < 64; o <<= 1) d += __shfl_xor(d, o);
  if (l == 0) red[w] = d;
  __syncthreads();
  if (t == 0) {
    float e = (red[0] - red[1]) * (1.0f / 32.0f);
    float term;
    if (isPos) {
      term = e * e;
    } else {
      float mm = fmaxf(1.0f - e, 0.0f);
      term = mm * mm;
    }
    atomicAdd(out, term / (float)nP);
  }
}

// ---------------------------------------------------------------------------
extern "C" void kernel_launch(void* const* d_in, const int* in_sizes, int n_in,
                              void* d_out, int out_size, void* d_ws, size_t ws_size,
                              hipStream_t stream) {
  const float* x  = (const float*)d_in[0];
  const int*   ei = (const int*)d_in[1];
  const int*   ep = (const int*)d_in[2];
  const int*   en = (const int*)d_in[3];
  const float* W  = (const float*)d_in[4];
  float* out = (float*)d_out;

  int N  = in_sizes[0] / 128;   // 100000 nodes
  int nE = in_sizes[1] / 2;     // 1600000 edges
  int nP = in_sizes[2] / 2;     // 30000 pos (== neg)

  size_t zBytes   = (size_t)N * 256 * sizeof(float);
  size_t aggBytes = (size_t)N * 128 * sizeof(float);
  if (ws_size < zBytes + aggBytes) return;

  char* ws = (char*)d_ws;
  float* z   = (float*)ws;                 // written LAST (by gemm)
  float* agg = (float*)(ws + zBytes);

  // CSR temporaries overlaid inside the z region (dead before gemm)
  int* cnt        = (int*)ws;              // N
  int* offs       = cnt + N;               // N+1
  int* pos        = offs + N + 1;          // N
  int* bsum       = pos + N;               // <= 4096
  int* sorted_src = bsum + 4096;           // nE

  int nb = (N + 255) / 256;

  hipMemsetAsync(cnt, 0, (size_t)N * sizeof(int), stream);
  hipMemsetAsync(out, 0, sizeof(float) * out_size, stream);

  const int* src = ei;
  const int* dst = ei + nE;

  int eb = (nE + 255) / 256;
  sge_count<<<eb, 256, 0, stream>>>(dst, cnt, nE);
  sge_blocksum<<<nb, 256, 0, stream>>>(cnt, bsum, N);
  sge_scan_top<<<1, 64, 0, stream>>>(bsum, offs, nb, N, nE);
  sge_scan_block<<<nb, 256, 0, stream>>>(cnt, bsum, offs, pos, N);
  sge_fill<<<eb, 256, 0, stream>>>(src, dst, pos, sorted_src, nE);
  sge_gather<<<(N + 1) / 2, 256, 0, stream>>>(x, sorted_src, offs, agg, N);

  sge_gemm<<<(N + 31) / 32, 256, 0, stream>>>(agg, W, z);

  sge_energy<<<2 * nP, 128, 0, stream>>>(z, ep, en, out, nP);
}

// Round 7
// 1238.829 us; speedup vs baseline: 1.1509x; 1.1509x over previous
//
#include <hip/hip_runtime.h>
#include <hip/hip_bf16.h>

// ---------------------------------------------------------------------------
// Phase 1a: CSR build by dst, then gather-aggregate
// ---------------------------------------------------------------------------

__global__ __launch_bounds__(256) void sge_count(
    const int* __restrict__ dst, int* __restrict__ cnt, int nE) {
  int e = blockIdx.x * 256 + threadIdx.x;
  if (e >= nE) return;
  atomicAdd(&cnt[dst[e]], 1);
}

__global__ __launch_bounds__(256) void sge_blocksum(
    const int* __restrict__ cnt, int* __restrict__ bsum, int N) {
  int i = blockIdx.x * 256 + threadIdx.x;
  int v = (i < N) ? cnt[i] : 0;
#pragma unroll
  for (int o = 1; o < 64; o <<= 1) v += __shfl_xor(v, o);
  __shared__ int ws[4];
  int lane = threadIdx.x & 63, wid = threadIdx.x >> 6;
  if (lane == 0) ws[wid] = v;
  __syncthreads();
  if (threadIdx.x == 0)
    bsum[blockIdx.x] = ws[0] + ws[1] + ws[2] + ws[3];
}

__global__ __launch_bounds__(64) void sge_scan_top(
    int* __restrict__ bsum, int* __restrict__ offs, int nb, int N, int nE) {
  int lane = threadIdx.x;
  int carry = 0;
  for (int base = 0; base < nb; base += 64) {
    int i = base + lane;
    int v = (i < nb) ? bsum[i] : 0;
    int s = v;
#pragma unroll
    for (int o = 1; o < 64; o <<= 1) {
      int t = __shfl_up(s, o);
      if (lane >= o) s += t;
    }
    if (i < nb) bsum[i] = carry + s - v;  // exclusive
    carry += __shfl(s, 63);
  }
  if (lane == 0) offs[N] = nE;
}

__global__ __launch_bounds__(256) void sge_scan_block(
    const int* __restrict__ cnt, const int* __restrict__ bsum,
    int* __restrict__ offs, int* __restrict__ pos, int N) {
  int i = blockIdx.x * 256 + threadIdx.x;
  int v = (i < N) ? cnt[i] : 0;
  int lane = threadIdx.x & 63, wid = threadIdx.x >> 6;
  int s = v;
#pragma unroll
  for (int o = 1; o < 64; o <<= 1) {
    int t = __shfl_up(s, o);
    if (lane >= o) s += t;
  }
  __shared__ int ws[4];
  if (lane == 63) ws[wid] = s;
  __syncthreads();
  int wbase = 0;
  for (int w = 0; w < wid; ++w) wbase += ws[w];
  if (i < N) {
    int o = bsum[blockIdx.x] + wbase + s - v;
    offs[i] = o;
    pos[i] = o;
  }
}

__global__ __launch_bounds__(256) void sge_fill(
    const int* __restrict__ src, const int* __restrict__ dst,
    int* __restrict__ pos, int* __restrict__ sorted_src, int nE) {
  int e = blockIdx.x * 256 + threadIdx.x;
  if (e >= nE) return;
  int p = atomicAdd(&pos[dst[e]], 1);
  sorted_src[p] = src[e];
}

// 128 threads per node; 4-way unrolled independent accumulators
__global__ __launch_bounds__(256) void sge_gather(
    const float* __restrict__ x, const int* __restrict__ sorted_src,
    const int* __restrict__ offs, float* __restrict__ agg, int N) {
  int node = blockIdx.x * 2 + (threadIdx.x >> 7);
  int c = threadIdx.x & 127;
  if (node >= N) return;
  int e0 = offs[node], e1 = offs[node + 1];
  float a0 = 0.f, a1 = 0.f, a2 = 0.f, a3 = 0.f;
  int e = e0;
  for (; e + 4 <= e1; e += 4) {
    int s0 = sorted_src[e + 0];
    int s1 = sorted_src[e + 1];
    int s2 = sorted_src[e + 2];
    int s3 = sorted_src[e + 3];
    a0 += x[(size_t)s0 * 128 + c];
    a1 += x[(size_t)s1 * 128 + c];
    a2 += x[(size_t)s2 * 128 + c];
    a3 += x[(size_t)s3 * 128 + c];
  }
  for (; e < e1; ++e) a0 += x[(size_t)sorted_src[e] * 128 + c];
  float acc = (a0 + a1) + (a2 + a3);
  float dg = (float)(e1 - e0);
  agg[(size_t)node * 128 + c] = acc / fmaxf(dg, 1.0f);
}

// ---------------------------------------------------------------------------
// Phase 1b: z = agg @ W   [N,128]@[128,256] -> [N,256]
// v2: 4 waves x 8 rows each -> 8 (not 32) ds_read_b128 per k-step per thread.
// lane owns cols {lane, lane+64, lane+128, lane+192}; acc[8][4].
// ---------------------------------------------------------------------------
__global__ __launch_bounds__(256) void sge_gemm(
    const float* __restrict__ agg, const float* __restrict__ W,
    float* __restrict__ z) {
  __shared__ float xs[32][128];
  int n0 = blockIdx.x * 32;
  int t = threadIdx.x;
#pragma unroll
  for (int i = 0; i < 16; ++i) {
    int idx = t + i * 256;
    int r = idx >> 7;
    int c = idx & 127;
    xs[r][c] = agg[(long long)(n0 + r) * 128 + c];
  }
  __syncthreads();
  int wv = t >> 6, lane = t & 63;
  int r0 = wv * 8;
  float acc[8][4];
#pragma unroll
  for (int r = 0; r < 8; ++r)
#pragma unroll
    for (int q = 0; q < 4; ++q) acc[r][q] = 0.f;
  for (int k = 0; k < 128; k += 4) {
    float4 xv[8];
#pragma unroll
    for (int r = 0; r < 8; ++r) xv[r] = *(const float4*)&xs[r0 + r][k];
#pragma unroll
    for (int kk = 0; kk < 4; ++kk) {
      const float* Wr = W + (k + kk) * 256 + lane;
      float w0 = Wr[0], w1 = Wr[64], w2 = Wr[128], w3 = Wr[192];
#pragma unroll
      for (int r = 0; r < 8; ++r) {
        float xk = (kk == 0) ? xv[r].x
                 : (kk == 1) ? xv[r].y
                 : (kk == 2) ? xv[r].z : xv[r].w;
        acc[r][0] = fmaf(xk, w0, acc[r][0]);
        acc[r][1] = fmaf(xk, w1, acc[r][1]);
        acc[r][2] = fmaf(xk, w2, acc[r][2]);
        acc[r][3] = fmaf(xk, w3, acc[r][3]);
      }
    }
  }
#pragma unroll
  for (int r = 0; r < 8; ++r) {
    float* zr = z + (long long)(n0 + r0 + r) * 256 + lane;
#pragma unroll
    for (int q = 0; q < 4; ++q) zr[q * 64] = acc[r][q];
  }
}

// ---------------------------------------------------------------------------
// Phase 2 (v8): 2 pairs per 256-thread block (occupancy); DPP reductions
// (VALU pipe) replace shfl (DS pipe); direct squared-distance build.
// Per pair: wave0 = {xy->fab, yx->gba} (cross-half exchange, intra-wave),
//           wave1 = {xx->faa, yy->gbb} (self).
// ---------------------------------------------------------------------------
template <int CTRL>
__device__ __forceinline__ float dpp_max(float x) {
  int r = __builtin_amdgcn_update_dpp(__float_as_int(x), __float_as_int(x),
                                      CTRL, 0xF, 0xF, false);
  return fmaxf(x, __int_as_float(r));
}
template <int CTRL>
__device__ __forceinline__ float dpp_add(float x) {
  int r = __builtin_amdgcn_update_dpp(0, __float_as_int(x), CTRL, 0xF, 0xF, true);
  return x + __int_as_float(r);
}

__global__ __launch_bounds__(256, 8) void sge_energy(
    const float* __restrict__ z, const int* __restrict__ ep,
    const int* __restrict__ en, float* __restrict__ out, int nP) {
  __shared__ __align__(16) float zbuf[2][512];    // per pair: zx[256]|zy[256]
  __shared__ __align__(16) float Ebuf[2][2][64];  // per pair, per wave
  __shared__ float red[2][2];

  int t = threadIdx.x;
  int pl = t >> 7;        // pair-local index 0/1
  int tp = t & 127;       // thread within pair
  int w = tp >> 6;        // wave-in-pair: 0={xy,yx}, 1={xx,yy}
  int l = tp & 63;
  int row = l & 31;
  int own = l & 32;       // 0 = x-rows half, 32 = y-rows half

  int pair = blockIdx.x * 2 + pl;
  bool isPos = pair < nP;
  int idx = isPos ? pair : pair - nP;
  const int* E = isPos ? ep : en;
  int na = E[idx], nb = E[idx + nP];

  // stage both z rows of this pair (512 floats, 128 threads x float4)
  {
    const float4* za = (const float4*)(z + (size_t)na * 256);
    const float4* zb = (const float4*)(z + (size_t)nb * 256);
    ((float4*)zbuf[pl])[tp] = (tp < 64) ? za[tp] : zb[tp - 64];
  }
  __syncthreads();

  const float* zx = zbuf[pl];
  const float* zy = zbuf[pl] + 256;
  const float* zrow = (own ? zy : zx) + row * 8;
  bool colIsX = (w == 0) ? (own != 0) : (own == 0);
  const float* pcol = colIsX ? zx : zy;

  float xr[8];
  {
    float4 a0 = ((const float4*)zrow)[0];
    float4 a1 = ((const float4*)zrow)[1];
    xr[0] = a0.x; xr[1] = a0.y; xr[2] = a0.z; xr[3] = a0.w;
    xr[4] = a1.x; xr[5] = a1.y; xr[6] = a1.z; xr[7] = a1.w;
  }

  const float RLNE = 1.44269504088896340736f;  // log2(e)
  const float LN2 = 0.69314718055994530942f;
  const float LN32 = 3.46573590279972654709f;  // ln(32)
  const float K20 = RLNE / 10.0f;

  // build V = 2^(-C*k2_0) via direct squared distance (no norms, no C kept)
  float V[32];
#pragma unroll
  for (int j = 0; j < 32; ++j) {
    float4 a0 = ((const float4*)(pcol + j * 8))[0];
    float4 a1 = ((const float4*)(pcol + j * 8))[1];
    float d0 = xr[0] - a0.x, d1 = xr[1] - a0.y;
    float d2 = xr[2] - a0.z, d3 = xr[3] - a0.w;
    float d4 = xr[4] - a1.x, d5 = xr[5] - a1.y;
    float d6 = xr[6] - a1.z, d7 = xr[7] - a1.w;
    float sq = d0 * d0;
    sq = fmaf(d1, d1, sq); sq = fmaf(d2, d2, sq); sq = fmaf(d3, d3, sq);
    sq = fmaf(d4, d4, sq); sq = fmaf(d5, d5, sq); sq = fmaf(d6, d6, sq);
    sq = fmaf(d7, d7, sq);
    float C = __builtin_amdgcn_sqrtf(sq + 1e-8f);
    V[j] = __builtin_amdgcn_exp2f(-C * K20);
  }

  float* Ew = Ebuf[pl][w];
  int rb = (w == 0) ? (own ^ 32) : own;

  float P = 0.0f;
  float epsv = 10.0f;

#pragma unroll 1
  for (int it = 0; it < 9; ++it) {
    float eps = (it == 8) ? 0.05f : epsv;
    float k2 = RLNE / eps;
    float eln2 = eps * LN2;
    float c32 = eps * LN32;

    if (it == 8) {
      // eps 0.078125 -> 0.05: exponent scales by 1.5625
#pragma unroll
      for (int j = 0; j < 32; ++j)
        V[j] = __builtin_amdgcn_exp2f(1.5625f * __builtin_amdgcn_logf(V[j]));
    } else if (it > 0) {
#pragma unroll
      for (int j = 0; j < 32; ++j) V[j] *= V[j];
    }

    // per-half group max of P via DPP (VALU pipe), both halves -> SGPRs
    float m = P;
    m = dpp_max<0x111>(m);  // row_shr:1
    m = dpp_max<0x112>(m);  // row_shr:2
    m = dpp_max<0x114>(m);  // row_shr:4
    m = dpp_max<0x118>(m);  // row_shr:8
    m = dpp_max<0x142>(m);  // row_bcast15 -> lane31/63 hold group maxes
    float g0 = __int_as_float(__builtin_amdgcn_readlane(__float_as_int(m), 31));
    float g1 = __int_as_float(__builtin_amdgcn_readlane(__float_as_int(m), 63));
    float mOwn = own ? g1 : g0;
    float mRead = (w == 0) ? (own ? g0 : g1) : mOwn;

    Ew[l] = __builtin_amdgcn_exp2f((P - mOwn) * k2);
    __builtin_amdgcn_wave_barrier();

    float s0 = 0.f, s1 = 0.f, s2 = 0.f, s3 = 0.f;
#pragma unroll
    for (int jq = 0; jq < 8; ++jq) {
      float4 Ev = ((const float4*)(Ew + rb))[jq];
      s0 = fmaf(Ev.x, V[4 * jq + 0], s0);
      s1 = fmaf(Ev.y, V[4 * jq + 1], s1);
      s2 = fmaf(Ev.z, V[4 * jq + 2], s2);
      s3 = fmaf(Ev.w, V[4 * jq + 3], s3);
    }
    float s = fmaxf((s0 + s1) + (s2 + s3), 1e-37f);
    __builtin_amdgcn_wave_barrier();  // reads complete before next write

    P = 0.5f * (P + (c32 - mRead - eln2 * __builtin_amdgcn_logf(s)));
    epsv *= 0.5f;
  }

  // wave sums via DPP; energy = (sum_wave0 - sum_wave1)/32
  float d = P;
  d = dpp_add<0x111>(d);
  d = dpp_add<0x112>(d);
  d = dpp_add<0x114>(d);
  d = dpp_add<0x118>(d);
  d = dpp_add<0x142>(d);  // lane31 = sum(0..31), lane63 = sum(32..63)
  float s31 = __int_as_float(__builtin_amdgcn_readlane(__float_as_int(d), 31));
  float s63 = __int_as_float(__builtin_amdgcn_readlane(__float_as_int(d), 63));
  if (l == 0) red[pl][w] = s31 + s63;
  __syncthreads();
  if (tp == 0) {
    float e = (red[pl][0] - red[pl][1]) * (1.0f / 32.0f);
    float term;
    if (isPos) {
      term = e * e;
    } else {
      float mm = fmaxf(1.0f - e, 0.0f);
      term = mm * mm;
    }
    atomicAdd(out, term / (float)nP);
  }
}

// ---------------------------------------------------------------------------
extern "C" void kernel_launch(void* const* d_in, const int* in_sizes, int n_in,
                              void* d_out, int out_size, void* d_ws, size_t ws_size,
                              hipStream_t stream) {
  const float* x  = (const float*)d_in[0];
  const int*   ei = (const int*)d_in[1];
  const int*   ep = (const int*)d_in[2];
  const int*   en = (const int*)d_in[3];
  const float* W  = (const float*)d_in[4];
  float* out = (float*)d_out;

  int N  = in_sizes[0] / 128;   // 100000 nodes
  int nE = in_sizes[1] / 2;     // 1600000 edges
  int nP = in_sizes[2] / 2;     // 30000 pos (== neg)

  size_t zBytes   = (size_t)N * 256 * sizeof(float);
  size_t aggBytes = (size_t)N * 128 * sizeof(float);
  if (ws_size < zBytes + aggBytes) return;

  char* ws = (char*)d_ws;
  float* z   = (float*)ws;                 // written LAST (by gemm)
  float* agg = (float*)(ws + zBytes);

  // CSR temporaries overlaid inside the z region (dead before gemm)
  int* cnt        = (int*)ws;              // N
  int* offs       = cnt + N;               // N+1
  int* pos        = offs + N + 1;          // N
  int* bsum       = pos + N;               // <= 4096
  int* sorted_src = bsum + 4096;           // nE

  int nb = (N + 255) / 256;

  hipMemsetAsync(cnt, 0, (size_t)N * sizeof(int), stream);
  hipMemsetAsync(out, 0, sizeof(float) * out_size, stream);

  const int* src = ei;
  const int* dst = ei + nE;

  int eb = (nE + 255) / 256;
  sge_count<<<eb, 256, 0, stream>>>(dst, cnt, nE);
  sge_blocksum<<<nb, 256, 0, stream>>>(cnt, bsum, N);
  sge_scan_top<<<1, 64, 0, stream>>>(bsum, offs, nb, N, nE);
  sge_scan_block<<<nb, 256, 0, stream>>>(cnt, bsum, offs, pos, N);
  sge_fill<<<eb, 256, 0, stream>>>(src, dst, pos, sorted_src, nE);
  sge_gather<<<(N + 1) / 2, 256, 0, stream>>>(x, sorted_src, offs, agg, N);

  sge_gemm<<<(N + 31) / 32, 256, 0, stream>>>(agg, W, z);

  sge_energy<<<nP, 256, 0, stream>>>(z, ep, en, out, nP);
}

// Round 8
// 1208.181 us; speedup vs baseline: 1.1801x; 1.0254x over previous
//
#include <hip/hip_runtime.h>
#include <hip/hip_bf16.h>

// ---------------------------------------------------------------------------
// Phase 1a: CSR build by dst, then gather-aggregate
// ---------------------------------------------------------------------------

__global__ __launch_bounds__(256) void sge_count(
    const int* __restrict__ dst, int* __restrict__ cnt, int nE) {
  int e = blockIdx.x * 256 + threadIdx.x;
  if (e >= nE) return;
  atomicAdd(&cnt[dst[e]], 1);
}

__global__ __launch_bounds__(256) void sge_blocksum(
    const int* __restrict__ cnt, int* __restrict__ bsum, int N) {
  int i = blockIdx.x * 256 + threadIdx.x;
  int v = (i < N) ? cnt[i] : 0;
#pragma unroll
  for (int o = 1; o < 64; o <<= 1) v += __shfl_xor(v, o);
  __shared__ int ws[4];
  int lane = threadIdx.x & 63, wid = threadIdx.x >> 6;
  if (lane == 0) ws[wid] = v;
  __syncthreads();
  if (threadIdx.x == 0)
    bsum[blockIdx.x] = ws[0] + ws[1] + ws[2] + ws[3];
}

__global__ __launch_bounds__(64) void sge_scan_top(
    int* __restrict__ bsum, int* __restrict__ offs, int nb, int N, int nE) {
  int lane = threadIdx.x;
  int carry = 0;
  for (int base = 0; base < nb; base += 64) {
    int i = base + lane;
    int v = (i < nb) ? bsum[i] : 0;
    int s = v;
#pragma unroll
    for (int o = 1; o < 64; o <<= 1) {
      int t = __shfl_up(s, o);
      if (lane >= o) s += t;
    }
    if (i < nb) bsum[i] = carry + s - v;  // exclusive
    carry += __shfl(s, 63);
  }
  if (lane == 0) offs[N] = nE;
}

__global__ __launch_bounds__(256) void sge_scan_block(
    const int* __restrict__ cnt, const int* __restrict__ bsum,
    int* __restrict__ offs, int* __restrict__ pos, int N) {
  int i = blockIdx.x * 256 + threadIdx.x;
  int v = (i < N) ? cnt[i] : 0;
  int lane = threadIdx.x & 63, wid = threadIdx.x >> 6;
  int s = v;
#pragma unroll
  for (int o = 1; o < 64; o <<= 1) {
    int t = __shfl_up(s, o);
    if (lane >= o) s += t;
  }
  __shared__ int ws[4];
  if (lane == 63) ws[wid] = s;
  __syncthreads();
  int wbase = 0;
  for (int w = 0; w < wid; ++w) wbase += ws[w];
  if (i < N) {
    int o = bsum[blockIdx.x] + wbase + s - v;
    offs[i] = o;
    pos[i] = o;
  }
}

__global__ __launch_bounds__(256) void sge_fill(
    const int* __restrict__ src, const int* __restrict__ dst,
    int* __restrict__ pos, int* __restrict__ sorted_src, int nE) {
  int e = blockIdx.x * 256 + threadIdx.x;
  if (e >= nE) return;
  int p = atomicAdd(&pos[dst[e]], 1);
  sorted_src[p] = src[e];
}

// 128 threads per node; 4-way unrolled independent accumulators
__global__ __launch_bounds__(256) void sge_gather(
    const float* __restrict__ x, const int* __restrict__ sorted_src,
    const int* __restrict__ offs, float* __restrict__ agg, int N) {
  int node = blockIdx.x * 2 + (threadIdx.x >> 7);
  int c = threadIdx.x & 127;
  if (node >= N) return;
  int e0 = offs[node], e1 = offs[node + 1];
  float a0 = 0.f, a1 = 0.f, a2 = 0.f, a3 = 0.f;
  int e = e0;
  for (; e + 4 <= e1; e += 4) {
    int s0 = sorted_src[e + 0];
    int s1 = sorted_src[e + 1];
    int s2 = sorted_src[e + 2];
    int s3 = sorted_src[e + 3];
    a0 += x[(size_t)s0 * 128 + c];
    a1 += x[(size_t)s1 * 128 + c];
    a2 += x[(size_t)s2 * 128 + c];
    a3 += x[(size_t)s3 * 128 + c];
  }
  for (; e < e1; ++e) a0 += x[(size_t)sorted_src[e] * 128 + c];
  float acc = (a0 + a1) + (a2 + a3);
  float dg = (float)(e1 - e0);
  agg[(size_t)node * 128 + c] = acc / fmaxf(dg, 1.0f);
}

// ---------------------------------------------------------------------------
// Phase 1b: z = agg @ W   [N,128]@[128,256] -> [N,256]
// 4 waves x 8 rows each; lane owns cols {lane, lane+64, lane+128, lane+192}.
// ---------------------------------------------------------------------------
__global__ __launch_bounds__(256) void sge_gemm(
    const float* __restrict__ agg, const float* __restrict__ W,
    float* __restrict__ z) {
  __shared__ float xs[32][128];
  int n0 = blockIdx.x * 32;
  int t = threadIdx.x;
#pragma unroll
  for (int i = 0; i < 16; ++i) {
    int idx = t + i * 256;
    int r = idx >> 7;
    int c = idx & 127;
    xs[r][c] = agg[(long long)(n0 + r) * 128 + c];
  }
  __syncthreads();
  int wv = t >> 6, lane = t & 63;
  int r0 = wv * 8;
  float acc[8][4];
#pragma unroll
  for (int r = 0; r < 8; ++r)
#pragma unroll
    for (int q = 0; q < 4; ++q) acc[r][q] = 0.f;
  for (int k = 0; k < 128; k += 4) {
    float4 xv[8];
#pragma unroll
    for (int r = 0; r < 8; ++r) xv[r] = *(const float4*)&xs[r0 + r][k];
#pragma unroll
    for (int kk = 0; kk < 4; ++kk) {
      const float* Wr = W + (k + kk) * 256 + lane;
      float w0 = Wr[0], w1 = Wr[64], w2 = Wr[128], w3 = Wr[192];
#pragma unroll
      for (int r = 0; r < 8; ++r) {
        float xk = (kk == 0) ? xv[r].x
                 : (kk == 1) ? xv[r].y
                 : (kk == 2) ? xv[r].z : xv[r].w;
        acc[r][0] = fmaf(xk, w0, acc[r][0]);
        acc[r][1] = fmaf(xk, w1, acc[r][1]);
        acc[r][2] = fmaf(xk, w2, acc[r][2]);
        acc[r][3] = fmaf(xk, w3, acc[r][3]);
      }
    }
  }
#pragma unroll
  for (int r = 0; r < 8; ++r) {
    float* zr = z + (long long)(n0 + r0 + r) * 256 + lane;
#pragma unroll
    for (int q = 0; q < 4; ++q) zr[q * 64] = acc[r][q];
  }
}

// ---------------------------------------------------------------------------
// Phase 2 (v9): v8 structure, but launch_bounds(256,4) -> 128-VGPR budget,
// fits the V[32] live set with ZERO scratch spill (R7's 219MB WRITE_SIZE was
// spill traffic from the forced 64-reg budget).
// ---------------------------------------------------------------------------
template <int CTRL>
__device__ __forceinline__ float dpp_max(float x) {
  int r = __builtin_amdgcn_update_dpp(__float_as_int(x), __float_as_int(x),
                                      CTRL, 0xF, 0xF, false);
  return fmaxf(x, __int_as_float(r));
}
template <int CTRL>
__device__ __forceinline__ float dpp_add(float x) {
  int r = __builtin_amdgcn_update_dpp(0, __float_as_int(x), CTRL, 0xF, 0xF, true);
  return x + __int_as_float(r);
}

__global__ __launch_bounds__(256, 4) void sge_energy(
    const float* __restrict__ z, const int* __restrict__ ep,
    const int* __restrict__ en, float* __restrict__ out, int nP) {
  __shared__ __align__(16) float zbuf[2][512];    // per pair: zx[256]|zy[256]
  __shared__ __align__(16) float Ebuf[2][2][64];  // per pair, per wave
  __shared__ float red[2][2];

  int t = threadIdx.x;
  int pl = t >> 7;        // pair-local index 0/1
  int tp = t & 127;       // thread within pair
  int w = tp >> 6;        // wave-in-pair: 0={xy,yx}, 1={xx,yy}
  int l = tp & 63;
  int row = l & 31;
  int own = l & 32;       // 0 = x-rows half, 32 = y-rows half

  int pair = blockIdx.x * 2 + pl;
  bool isPos = pair < nP;
  int idx = isPos ? pair : pair - nP;
  const int* E = isPos ? ep : en;
  int na = E[idx], nb = E[idx + nP];

  // stage both z rows of this pair (512 floats, 128 threads x float4)
  {
    const float4* za = (const float4*)(z + (size_t)na * 256);
    const float4* zb = (const float4*)(z + (size_t)nb * 256);
    ((float4*)zbuf[pl])[tp] = (tp < 64) ? za[tp] : zb[tp - 64];
  }
  __syncthreads();

  const float* zx = zbuf[pl];
  const float* zy = zbuf[pl] + 256;
  const float* zrow = (own ? zy : zx) + row * 8;
  bool colIsX = (w == 0) ? (own != 0) : (own == 0);
  const float* pcol = colIsX ? zx : zy;

  float xr[8];
  {
    float4 a0 = ((const float4*)zrow)[0];
    float4 a1 = ((const float4*)zrow)[1];
    xr[0] = a0.x; xr[1] = a0.y; xr[2] = a0.z; xr[3] = a0.w;
    xr[4] = a1.x; xr[5] = a1.y; xr[6] = a1.z; xr[7] = a1.w;
  }

  const float RLNE = 1.44269504088896340736f;  // log2(e)
  const float LN2 = 0.69314718055994530942f;
  const float LN32 = 3.46573590279972654709f;  // ln(32)
  const float K20 = RLNE / 10.0f;

  // build V = 2^(-C*k2_0) via direct squared distance (no norms, no C kept)
  float V[32];
#pragma unroll
  for (int j = 0; j < 32; ++j) {
    float4 a0 = ((const float4*)(pcol + j * 8))[0];
    float4 a1 = ((const float4*)(pcol + j * 8))[1];
    float d0 = xr[0] - a0.x, d1 = xr[1] - a0.y;
    float d2 = xr[2] - a0.z, d3 = xr[3] - a0.w;
    float d4 = xr[4] - a1.x, d5 = xr[5] - a1.y;
    float d6 = xr[6] - a1.z, d7 = xr[7] - a1.w;
    float sq = d0 * d0;
    sq = fmaf(d1, d1, sq); sq = fmaf(d2, d2, sq); sq = fmaf(d3, d3, sq);
    sq = fmaf(d4, d4, sq); sq = fmaf(d5, d5, sq); sq = fmaf(d6, d6, sq);
    sq = fmaf(d7, d7, sq);
    float C = __builtin_amdgcn_sqrtf(sq + 1e-8f);
    V[j] = __builtin_amdgcn_exp2f(-C * K20);
  }

  float* Ew = Ebuf[pl][w];
  int rb = (w == 0) ? (own ^ 32) : own;

  float P = 0.0f;
  float epsv = 10.0f;

#pragma unroll 1
  for (int it = 0; it < 9; ++it) {
    float eps = (it == 8) ? 0.05f : epsv;
    float k2 = RLNE / eps;
    float eln2 = eps * LN2;
    float c32 = eps * LN32;

    if (it == 8) {
      // eps 0.078125 -> 0.05: exponent scales by 1.5625
#pragma unroll
      for (int j = 0; j < 32; ++j)
        V[j] = __builtin_amdgcn_exp2f(1.5625f * __builtin_amdgcn_logf(V[j]));
    } else if (it > 0) {
#pragma unroll
      for (int j = 0; j < 32; ++j) V[j] *= V[j];
    }

    // per-half group max of P via DPP (VALU pipe), both halves -> SGPRs
    float m = P;
    m = dpp_max<0x111>(m);  // row_shr:1
    m = dpp_max<0x112>(m);  // row_shr:2
    m = dpp_max<0x114>(m);  // row_shr:4
    m = dpp_max<0x118>(m);  // row_shr:8
    m = dpp_max<0x142>(m);  // row_bcast15 -> lane31/63 hold group maxes
    float g0 = __int_as_float(__builtin_amdgcn_readlane(__float_as_int(m), 31));
    float g1 = __int_as_float(__builtin_amdgcn_readlane(__float_as_int(m), 63));
    float mOwn = own ? g1 : g0;
    float mRead = (w == 0) ? (own ? g0 : g1) : mOwn;

    Ew[l] = __builtin_amdgcn_exp2f((P - mOwn) * k2);
    __builtin_amdgcn_wave_barrier();

    float s0 = 0.f, s1 = 0.f, s2 = 0.f, s3 = 0.f;
#pragma unroll
    for (int jq = 0; jq < 8; ++jq) {
      float4 Ev = ((const float4*)(Ew + rb))[jq];
      s0 = fmaf(Ev.x, V[4 * jq + 0], s0);
      s1 = fmaf(Ev.y, V[4 * jq + 1], s1);
      s2 = fmaf(Ev.z, V[4 * jq + 2], s2);
      s3 = fmaf(Ev.w, V[4 * jq + 3], s3);
    }
    float s = fmaxf((s0 + s1) + (s2 + s3), 1e-37f);
    __builtin_amdgcn_wave_barrier();  // reads complete before next write

    P = 0.5f * (P + (c32 - mRead - eln2 * __builtin_amdgcn_logf(s)));
    epsv *= 0.5f;
  }

  // wave sums via DPP; energy = (sum_wave0 - sum_wave1)/32
  float d = P;
  d = dpp_add<0x111>(d);
  d = dpp_add<0x112>(d);
  d = dpp_add<0x114>(d);
  d = dpp_add<0x118>(d);
  d = dpp_add<0x142>(d);  // lane31 = sum(0..31), lane63 = sum(32..63)
  float s31 = __int_as_float(__builtin_amdgcn_readlane(__float_as_int(d), 31));
  float s63 = __int_as_float(__builtin_amdgcn_readlane(__float_as_int(d), 63));
  if (l == 0) red[pl][w] = s31 + s63;
  __syncthreads();
  if (tp == 0) {
    float e = (red[pl][0] - red[pl][1]) * (1.0f / 32.0f);
    float term;
    if (isPos) {
      term = e * e;
    } else {
      float mm = fmaxf(1.0f - e, 0.0f);
      term = mm * mm;
    }
    atomicAdd(out, term / (float)nP);
  }
}

// ---------------------------------------------------------------------------
extern "C" void kernel_launch(void* const* d_in, const int* in_sizes, int n_in,
                              void* d_out, int out_size, void* d_ws, size_t ws_size,
                              hipStream_t stream) {
  const float* x  = (const float*)d_in[0];
  const int*   ei = (const int*)d_in[1];
  const int*   ep = (const int*)d_in[2];
  const int*   en = (const int*)d_in[3];
  const float* W  = (const float*)d_in[4];
  float* out = (float*)d_out;

  int N  = in_sizes[0] / 128;   // 100000 nodes
  int nE = in_sizes[1] / 2;     // 1600000 edges
  int nP = in_sizes[2] / 2;     // 30000 pos (== neg)

  size_t zBytes   = (size_t)N * 256 * sizeof(float);
  size_t aggBytes = (size_t)N * 128 * sizeof(float);
  if (ws_size < zBytes + aggBytes) return;

  char* ws = (char*)d_ws;
  float* z   = (float*)ws;                 // written LAST (by gemm)
  float* agg = (float*)(ws + zBytes);

  // CSR temporaries overlaid inside the z region (dead before gemm)
  int* cnt        = (int*)ws;              // N
  int* offs       = cnt + N;               // N+1
  int* pos        = offs + N + 1;          // N
  int* bsum       = pos + N;               // <= 4096
  int* sorted_src = bsum + 4096;           // nE

  int nb = (N + 255) / 256;

  hipMemsetAsync(cnt, 0, (size_t)N * sizeof(int), stream);
  hipMemsetAsync(out, 0, sizeof(float) * out_size, stream);

  const int* src = ei;
  const int* dst = ei + nE;

  int eb = (nE + 255) / 256;
  sge_count<<<eb, 256, 0, stream>>>(dst, cnt, nE);
  sge_blocksum<<<nb, 256, 0, stream>>>(cnt, bsum, N);
  sge_scan_top<<<1, 64, 0, stream>>>(bsum, offs, nb, N, nE);
  sge_scan_block<<<nb, 256, 0, stream>>>(cnt, bsum, offs, pos, N);
  sge_fill<<<eb, 256, 0, stream>>>(src, dst, pos, sorted_src, nE);
  sge_gather<<<(N + 1) / 2, 256, 0, stream>>>(x, sorted_src, offs, agg, N);

  sge_gemm<<<(N + 31) / 32, 256, 0, stream>>>(agg, W, z);

  sge_energy<<<nP, 256, 0, stream>>>(z, ep, en, out, nP);
}